// Round 6
// baseline (904.598 us; speedup 1.0000x reference)
//
#include <hip/hip_runtime.h>
#include <cmath>

typedef _Float16 f16;
typedef _Float16 f16x8 __attribute__((ext_vector_type(8)));
typedef float f32x4 __attribute__((ext_vector_type(4)));
typedef unsigned long long u64;

#define M_OUT 2049          // N//2 + 1
#define NDIM 4096
#define MPAD 2112           // 2049 padded to 64-multiple (33 tiles)
// reference: -2.0 * 3.14 / N computed in f64, rounded once to f32
#define CW ((float)(-2.0 * 3.14 / 4096.0))

// ws layout:
//   [0, 16384)             row means (4096 f32)
//   [16384, 16384+2049*8)  argmax cells (u64, packed (amp2_bits<<32)|~col)
//   [40960, ...)           tables (layout depends on path)
// FULL path (chunk-major; a lane's MFMA fragment = one contiguous 16B line):
//   A tables: Ach,Acl,Ash,Asl each [512][2112][8] f16   (4 x 17.3 MB)
//   X tables: Xh,Xl           each [512][4096][8] f16   (2 x 33.6 MB)
// MID path (row-major): Ach,Acl,Ash,Asl each [2112][4096] f16
static const size_t WS_MEAN  = 0;
static const size_t WS_CELLS = 16384;
static const size_t WS_TBL   = 40960;
static const size_t A_ELEMS  = (size_t)MPAD * NDIM;        // 8650752
static const size_t X_ELEMS  = (size_t)NDIM * NDIM;        // 16777216
static const size_t WS_XTBL  = WS_TBL + 4 * A_ELEMS * sizeof(f16);
static const size_t WS_FULL_END = WS_XTBL + 2 * X_ELEMS * sizeof(f16);
static const size_t WS_MID_END  = WS_TBL + 4 * A_ELEMS * sizeof(f16);

__device__ __forceinline__ void split_f16(float v, f16& hi, f16& lo) {
    hi = (f16)v;
    lo = (f16)((v - (float)hi) * 64.0f);
}

// ---------------- row means ----------------
__global__ void mean_kernel(const float* __restrict__ x, float* __restrict__ meanv) {
    const int row = blockIdx.x;
    const float4* xr = (const float4*)(x + (size_t)row * NDIM);
    float s = 0.f;
    for (int i = threadIdx.x; i < NDIM / 4; i += 256) {
        float4 v = xr[i];
        s += (v.x + v.y) + (v.z + v.w);
    }
    for (int off = 32; off; off >>= 1) s += __shfl_down(s, off);
    __shared__ float ps[4];
    if ((threadIdx.x & 63) == 0) ps[threadIdx.x >> 6] = s;
    __syncthreads();
    if (threadIdx.x == 0) {
        float t = (ps[0] + ps[1]) + (ps[2] + ps[3]);
        meanv[row] = t * (1.0f / 4096.0f);
    }
}

// ---------------- init argmax cells ----------------
__global__ void init_cells(u64* __restrict__ cells) {
    int i = blockIdx.x * 256 + threadIdx.x;
    if (i < M_OUT) cells[i] = 0ull;
}

// ================= FULL path: chunk-major tables =================
__global__ void fill_A_cm(f16* __restrict__ tbl) {
    const int c = blockIdx.x;                      // k-chunk 0..511
    const int m = blockIdx.y * 256 + threadIdx.x;  // 0..2303
    if (m >= MPAD) return;
    const bool valid = (m < M_OUT);
    f16x8 chv, clv, shv, slv;
    for (int j = 0; j < 8; ++j) {
        float cc = 0.f, ss = 0.f;
        if (valid) {
            int kk = c * 8 + j;
            float ang = CW * (float)(m * kk);      // m*kk < 2^24 -> exact
            sincosf(ang, &ss, &cc);
        }
        f16 h, l;
        split_f16(cc, h, l); chv[j] = h; clv[j] = l;
        split_f16(ss, h, l); shv[j] = h; slv[j] = l;
    }
    size_t idx = ((size_t)c * MPAD + m) * 8;
    *(f16x8*)(tbl + idx)                 = chv;
    *(f16x8*)(tbl + A_ELEMS + idx)       = clv;
    *(f16x8*)(tbl + 2 * A_ELEMS + idx)   = shv;
    *(f16x8*)(tbl + 3 * A_ELEMS + idx)   = slv;
}

__global__ void fill_X_cm(const float* __restrict__ x, const float* __restrict__ meanv,
                          f16* __restrict__ xtbl) {
    const int c = blockIdx.x;                      // k-chunk 0..511
    const int n = blockIdx.y * 256 + threadIdx.x;  // 0..4095
    f16x8 hv, lv;
    for (int j = 0; j < 8; ++j) {
        int k = c * 8 + j;
        float v = x[(size_t)k * NDIM + n] - meanv[k];
        f16 h, l;
        split_f16(v, h, l);
        hv[j] = h; lv[j] = l;
    }
    size_t idx = ((size_t)c * NDIM + n) * 8;
    *(f16x8*)(xtbl + idx)           = hv;
    *(f16x8*)(xtbl + X_ELEMS + idx) = lv;
}

// Fused split-f16 DFT GEMM + argmax — REGISTER-DIRECT, NO LDS, NO BARRIERS.
// Both A and X fragments are contiguous 16B lines in the chunk-major tables,
// loaded global->VGPR. Waves self-stagger (no __syncthreads in the K-loop),
// so the compiler's fine-grained vmcnt scheduling + cross-wave MFMA/VMEM
// co-issue hides the cache latency. Duplicate fragment reads (wm-pair shares
// X, wn-pair shares A) are served by L1/L2.
// Tile: BM=64 x BN=128 x BK=32/iter. 256 threads = 4 waves (2x2 of 32x64).
__global__ __launch_bounds__(256, 3) void dft_gemm_reg(
    const f16* __restrict__ atbl, const f16* __restrict__ xtbl,
    u64* __restrict__ cells)
{
    const int t = threadIdx.x;
    const int n0      = blockIdx.x * 128;
    const int rowBase = blockIdx.y * 64;

    const int lane = t & 63;
    const int w  = t >> 6;
    const int wm = w >> 1, wn = w & 1;
    const int q  = lane >> 4, ln = lane & 15;

    f32x4 aC0[2][4], aC1[2][4], aS0[2][4], aS1[2][4];
#pragma unroll
    for (int i = 0; i < 2; ++i)
#pragma unroll
        for (int j = 0; j < 4; ++j) {
            aC0[i][j] = (f32x4){0.f, 0.f, 0.f, 0.f};
            aC1[i][j] = (f32x4){0.f, 0.f, 0.f, 0.f};
            aS0[i][j] = (f32x4){0.f, 0.f, 0.f, 0.f};
            aS1[i][j] = (f32x4){0.f, 0.f, 0.f, 0.f};
        }

    // lane-fragment base pointers (chunk = q, advancing by 4 chunks per iter)
    const f16* aP = atbl + ((size_t)q * MPAD + (rowBase + wm * 32 + ln)) * 8;
    const f16* xP = xtbl + ((size_t)q * NDIM + (n0 + wn * 64 + ln)) * 8;
    const size_t aStep = (size_t)4 * MPAD * 8;
    const size_t xStep = (size_t)4 * NDIM * 8;

    for (int kc = 0; kc < 512; kc += 4) {
        f16x8 A[2][4], bh[4], bl[4];
#pragma unroll
        for (int tm = 0; tm < 2; ++tm)
#pragma unroll
            for (int tb = 0; tb < 4; ++tb)
                A[tm][tb] = *(const f16x8*)(aP + (size_t)tb * A_ELEMS + (size_t)tm * 16 * 8);
#pragma unroll
        for (int tn = 0; tn < 4; ++tn) {
            bh[tn] = *(const f16x8*)(xP + (size_t)tn * 16 * 8);
            bl[tn] = *(const f16x8*)(xP + X_ELEMS + (size_t)tn * 16 * 8);
        }
#pragma unroll
        for (int tm = 0; tm < 2; ++tm)
#pragma unroll
            for (int tn = 0; tn < 4; ++tn) {
                aC0[tm][tn] = __builtin_amdgcn_mfma_f32_16x16x32_f16(A[tm][0], bh[tn], aC0[tm][tn], 0, 0, 0);
                aC1[tm][tn] = __builtin_amdgcn_mfma_f32_16x16x32_f16(A[tm][0], bl[tn], aC1[tm][tn], 0, 0, 0);
                aC1[tm][tn] = __builtin_amdgcn_mfma_f32_16x16x32_f16(A[tm][1], bh[tn], aC1[tm][tn], 0, 0, 0);
                aS0[tm][tn] = __builtin_amdgcn_mfma_f32_16x16x32_f16(A[tm][2], bh[tn], aS0[tm][tn], 0, 0, 0);
                aS1[tm][tn] = __builtin_amdgcn_mfma_f32_16x16x32_f16(A[tm][2], bl[tn], aS1[tm][tn], 0, 0, 0);
                aS1[tm][tn] = __builtin_amdgcn_mfma_f32_16x16x32_f16(A[tm][3], bh[tn], aS1[tm][tn], 0, 0, 0);
            }
        aP += aStep;
        xP += xStep;
    }

    // ---- epilogue: amp^2, per-row argmax, atomicMax into cells ----
    const float inv64 = 0.015625f;
#pragma unroll
    for (int tm = 0; tm < 2; ++tm) {
#pragma unroll
        for (int r = 0; r < 4; ++r) {
            u64 best = 0ull;
#pragma unroll
            for (int tn = 0; tn < 4; ++tn) {
                float C = aC0[tm][tn][r] + aC1[tm][tn][r] * inv64;
                float S = aS0[tm][tn][r] + aS1[tm][tn][r] * inv64;
                float a2 = C * C + S * S;
                int col = n0 + wn * 64 + tn * 16 + ln;
                u64 key = ((u64)__float_as_uint(a2) << 32) | (unsigned)(~col);
                if (key > best) best = key;
            }
            for (int off = 1; off < 16; off <<= 1) {
                unsigned hi = (unsigned)(best >> 32), lo = (unsigned)best;
                unsigned ho = __shfl_xor(hi, off);
                unsigned lo2 = __shfl_xor(lo, off);
                u64 o = ((u64)ho << 32) | lo2;
                if (o > best) best = o;
            }
            if (ln == 0) {
                int grow = rowBase + wm * 32 + tm * 16 + q * 4 + r;
                if (grow < M_OUT) atomicMax(cells + grow, best);
            }
        }
    }
}

// ================= MID/LOW fallback path =================
__global__ void fill_tables_rm(f16* __restrict__ tbl) {
    long long g = (long long)blockIdx.x * 256 + threadIdx.x;
    if (g >= (long long)(MPAD * 512)) return;
    int m  = (int)(g >> 9);
    int kq = ((int)g & 511) * 8;
    bool valid = (m < M_OUT);
    f16x8 chv, clv, shv, slv;
    for (int j = 0; j < 8; ++j) {
        float c = 0.f, s = 0.f;
        if (valid) {
            int kk = kq + j;
            float ang = CW * (float)(m * kk);
            sincosf(ang, &s, &c);
        }
        f16 h, l;
        split_f16(c, h, l); chv[j] = h; clv[j] = l;
        split_f16(s, h, l); shv[j] = h; slv[j] = l;
    }
    size_t idx = (size_t)m * NDIM + kq;
    *(f16x8*)(tbl + idx)               = chv;
    *(f16x8*)(tbl + A_ELEMS + idx)     = clv;
    *(f16x8*)(tbl + 2 * A_ELEMS + idx) = shv;
    *(f16x8*)(tbl + 3 * A_ELEMS + idx) = slv;
}

#define PK 40   // padded k-stride: all 8 bank groups covered -> 2-way (free)
__global__ __launch_bounds__(256, 2) void dft_gemm_fb(
    const float* __restrict__ x, const float* __restrict__ meanv,
    const f16* __restrict__ tbl, int useTbl,
    u64* __restrict__ cells)
{
    __shared__ alignas(16) f16 Ach[64][PK];
    __shared__ alignas(16) f16 Acl[64][PK];
    __shared__ alignas(16) f16 Ash[64][PK];
    __shared__ alignas(16) f16 Asl[64][PK];
    __shared__ alignas(16) f16 Xh[128][PK];
    __shared__ alignas(16) f16 Xl[128][PK];

    const int t = threadIdx.x;
    const int n0      = blockIdx.x * 128;
    const int rowBase = blockIdx.y * 64;

    const int am  = t >> 2;
    const int akq = (t & 3) * 8;
    const int xn  = t & 127;
    const int xkh = (t >> 7) * 16;

    const int lane = t & 63;
    const int w  = t >> 6;
    const int wm = w >> 1, wn = w & 1;
    const int q  = lane >> 4, ln = lane & 15;

    f32x4 aC0[2][4], aC1[2][4], aS0[2][4], aS1[2][4];
    for (int i = 0; i < 2; ++i)
        for (int j = 0; j < 4; ++j) {
            aC0[i][j] = (f32x4){0.f, 0.f, 0.f, 0.f};
            aC1[i][j] = (f32x4){0.f, 0.f, 0.f, 0.f};
            aS0[i][j] = (f32x4){0.f, 0.f, 0.f, 0.f};
            aS1[i][j] = (f32x4){0.f, 0.f, 0.f, 0.f};
        }

    const int arow = rowBase + am;
    const bool avalid = (arow < M_OUT);

    for (int k0 = 0; k0 < NDIM; k0 += 32) {
        __syncthreads();
        if (useTbl) {
            size_t idx = (size_t)arow * NDIM + k0 + akq;
            *(f16x8*)&Ach[am][akq] = *(const f16x8*)(tbl + idx);
            *(f16x8*)&Acl[am][akq] = *(const f16x8*)(tbl + A_ELEMS + idx);
            *(f16x8*)&Ash[am][akq] = *(const f16x8*)(tbl + 2 * A_ELEMS + idx);
            *(f16x8*)&Asl[am][akq] = *(const f16x8*)(tbl + 3 * A_ELEMS + idx);
        } else {
            f16x8 chv, clv, shv, slv;
            for (int j = 0; j < 8; ++j) {
                float c = 0.f, s = 0.f;
                if (avalid) {
                    int kk = k0 + akq + j;
                    float ang = CW * (float)(arow * kk);
                    sincosf(ang, &s, &c);
                }
                f16 h, l;
                split_f16(c, h, l); chv[j] = h; clv[j] = l;
                split_f16(s, h, l); shv[j] = h; slv[j] = l;
            }
            *(f16x8*)&Ach[am][akq] = chv;
            *(f16x8*)&Acl[am][akq] = clv;
            *(f16x8*)&Ash[am][akq] = shv;
            *(f16x8*)&Asl[am][akq] = slv;
        }
        {
            const float* xp = x + (size_t)(k0 + xkh) * NDIM + n0 + xn;
            f16x8 h0, h1, l0, l1;
            for (int r = 0; r < 16; ++r) {
                float v = xp[(size_t)r * NDIM] - meanv[k0 + xkh + r];
                f16 hi, lo;
                split_f16(v, hi, lo);
                if (r < 8) { h0[r] = hi; l0[r] = lo; }
                else       { h1[r - 8] = hi; l1[r - 8] = lo; }
            }
            *(f16x8*)&Xh[xn][xkh]     = h0;
            *(f16x8*)&Xh[xn][xkh + 8] = h1;
            *(f16x8*)&Xl[xn][xkh]     = l0;
            *(f16x8*)&Xl[xn][xkh + 8] = l1;
        }
        __syncthreads();
        f16x8 fch[2], fcl[2], fsh[2], fsl[2], bh[4], bl[4];
        for (int tm = 0; tm < 2; ++tm) {
            int ml = wm * 32 + tm * 16 + ln;
            fch[tm] = *(const f16x8*)&Ach[ml][q * 8];
            fcl[tm] = *(const f16x8*)&Acl[ml][q * 8];
            fsh[tm] = *(const f16x8*)&Ash[ml][q * 8];
            fsl[tm] = *(const f16x8*)&Asl[ml][q * 8];
        }
        for (int tn = 0; tn < 4; ++tn) {
            int nl = wn * 64 + tn * 16 + ln;
            bh[tn] = *(const f16x8*)&Xh[nl][q * 8];
            bl[tn] = *(const f16x8*)&Xl[nl][q * 8];
        }
        for (int tm = 0; tm < 2; ++tm)
            for (int tn = 0; tn < 4; ++tn) {
                aC0[tm][tn] = __builtin_amdgcn_mfma_f32_16x16x32_f16(fch[tm], bh[tn], aC0[tm][tn], 0, 0, 0);
                aC1[tm][tn] = __builtin_amdgcn_mfma_f32_16x16x32_f16(fch[tm], bl[tn], aC1[tm][tn], 0, 0, 0);
                aC1[tm][tn] = __builtin_amdgcn_mfma_f32_16x16x32_f16(fcl[tm], bh[tn], aC1[tm][tn], 0, 0, 0);
                aS0[tm][tn] = __builtin_amdgcn_mfma_f32_16x16x32_f16(fsh[tm], bh[tn], aS0[tm][tn], 0, 0, 0);
                aS1[tm][tn] = __builtin_amdgcn_mfma_f32_16x16x32_f16(fsh[tm], bl[tn], aS1[tm][tn], 0, 0, 0);
                aS1[tm][tn] = __builtin_amdgcn_mfma_f32_16x16x32_f16(fsl[tm], bh[tn], aS1[tm][tn], 0, 0, 0);
            }
    }

    const float inv64 = 0.015625f;
    for (int tm = 0; tm < 2; ++tm) {
        for (int r = 0; r < 4; ++r) {
            u64 best = 0ull;
            for (int tn = 0; tn < 4; ++tn) {
                float C = aC0[tm][tn][r] + aC1[tm][tn][r] * inv64;
                float S = aS0[tm][tn][r] + aS1[tm][tn][r] * inv64;
                float a2 = C * C + S * S;
                int col = n0 + wn * 64 + tn * 16 + ln;
                u64 key = ((u64)__float_as_uint(a2) << 32) | (unsigned)(~col);
                if (key > best) best = key;
            }
            for (int off = 1; off < 16; off <<= 1) {
                unsigned hi = (unsigned)(best >> 32), lo = (unsigned)best;
                unsigned ho = __shfl_xor(hi, off);
                unsigned lo2 = __shfl_xor(lo, off);
                u64 o = ((u64)ho << 32) | lo2;
                if (o > best) best = o;
            }
            if (ln == 0) {
                int grow = rowBase + wm * 32 + tm * 16 + q * 4 + r;
                if (grow < M_OUT) atomicMax(cells + grow, best);
            }
        }
    }
}

// ---------------- cells -> output ----------------
__global__ void out_kernel(const u64* __restrict__ cells, float* __restrict__ out) {
    int i = blockIdx.x * 256 + threadIdx.x;
    if (i < M_OUT) {
        unsigned col = ~(unsigned)(cells[i] & 0xFFFFFFFFull);
        float freq = (float)col / (4096.0f / 30.0f);
        out[i] = freq * 60.0f;
    }
}

extern "C" void kernel_launch(void* const* d_in, const int* in_sizes, int n_in,
                              void* d_out, int out_size, void* d_ws, size_t ws_size,
                              hipStream_t stream) {
    const float* x = (const float*)d_in[0];
    char* ws = (char*)d_ws;
    float* meanv = (float*)(ws + WS_MEAN);
    u64*   cells = (u64*)(ws + WS_CELLS);
    f16*   atbl  = (f16*)(ws + WS_TBL);
    f16*   xtbl  = (f16*)(ws + WS_XTBL);
    float* out   = (float*)d_out;

    hipLaunchKernelGGL(init_cells, dim3((M_OUT + 255) / 256), dim3(256), 0, stream, cells);
    hipLaunchKernelGGL(mean_kernel, dim3(NDIM), dim3(256), 0, stream, x, meanv);

    if (ws_size >= WS_FULL_END) {
        hipLaunchKernelGGL(fill_A_cm, dim3(512, 9), dim3(256), 0, stream, atbl);
        hipLaunchKernelGGL(fill_X_cm, dim3(512, 16), dim3(256), 0, stream, x, meanv, xtbl);
        hipLaunchKernelGGL(dft_gemm_reg, dim3(32, 33), dim3(256), 0, stream, atbl, xtbl, cells);
    } else if (ws_size >= WS_MID_END) {
        hipLaunchKernelGGL(fill_tables_rm, dim3(4224), dim3(256), 0, stream, atbl);
        hipLaunchKernelGGL(dft_gemm_fb, dim3(32, 33), dim3(256), 0, stream,
                           x, meanv, atbl, 1, cells);
    } else {
        hipLaunchKernelGGL(dft_gemm_fb, dim3(32, 33), dim3(256), 0, stream,
                           x, meanv, atbl, 0, cells);
    }
    hipLaunchKernelGGL(out_kernel, dim3((M_OUT + 255) / 256), dim3(256), 0, stream, cells, out);
}

// Round 7
// 541.571 us; speedup vs baseline: 1.6703x; 1.6703x over previous
//
#include <hip/hip_runtime.h>
#include <cmath>

typedef _Float16 f16;
typedef _Float16 f16x8 __attribute__((ext_vector_type(8)));
typedef float f32x4 __attribute__((ext_vector_type(4)));
typedef unsigned long long u64;

#define M_OUT 2049          // N//2 + 1
#define NDIM 4096
#define MPAD 2112           // 2049 padded to 64-multiple (33 tiles)
// reference: -2.0 * 3.14 / N computed in f64, rounded once to f32
#define CW ((float)(-2.0 * 3.14 / 4096.0))

// ws layout:
//   [0, 16384)             row means (4096 f32)
//   [16384, 16384+2049*8)  argmax cells (u64, packed (amp2_bits<<32)|~col)
//   [40960, ...)           tables (layout depends on path)
// FULL path (chunk-major; a lane's MFMA fragment = one contiguous 16B line):
//   A tables: Ach,Acl,Ash,Asl each [512][2112][8] f16   (4 x 17.3 MB)
//   X tables: Xh,Xl           each [512][4096][8] f16   (2 x 33.6 MB)
// MID path (row-major): Ach,Acl,Ash,Asl each [2112][4096] f16
static const size_t WS_MEAN  = 0;
static const size_t WS_CELLS = 16384;
static const size_t WS_TBL   = 40960;
static const size_t A_ELEMS  = (size_t)MPAD * NDIM;        // 8650752
static const size_t X_ELEMS  = (size_t)NDIM * NDIM;        // 16777216
static const size_t WS_XTBL  = WS_TBL + 4 * A_ELEMS * sizeof(f16);
static const size_t WS_FULL_END = WS_XTBL + 2 * X_ELEMS * sizeof(f16);
static const size_t WS_MID_END  = WS_TBL + 4 * A_ELEMS * sizeof(f16);

__device__ __forceinline__ void split_f16(float v, f16& hi, f16& lo) {
    hi = (f16)v;
    lo = (f16)((v - (float)hi) * 64.0f);
}

// ---------------- row means ----------------
__global__ void mean_kernel(const float* __restrict__ x, float* __restrict__ meanv) {
    const int row = blockIdx.x;
    const float4* xr = (const float4*)(x + (size_t)row * NDIM);
    float s = 0.f;
    for (int i = threadIdx.x; i < NDIM / 4; i += 256) {
        float4 v = xr[i];
        s += (v.x + v.y) + (v.z + v.w);
    }
    for (int off = 32; off; off >>= 1) s += __shfl_down(s, off);
    __shared__ float ps[4];
    if ((threadIdx.x & 63) == 0) ps[threadIdx.x >> 6] = s;
    __syncthreads();
    if (threadIdx.x == 0) {
        float t = (ps[0] + ps[1]) + (ps[2] + ps[3]);
        meanv[row] = t * (1.0f / 4096.0f);
    }
}

// ---------------- init argmax cells ----------------
__global__ void init_cells(u64* __restrict__ cells) {
    int i = blockIdx.x * 256 + threadIdx.x;
    if (i < M_OUT) cells[i] = 0ull;
}

// ================= FULL path: chunk-major tables =================
__global__ void fill_A_cm(f16* __restrict__ tbl) {
    const int c = blockIdx.x;                      // k-chunk 0..511
    const int m = blockIdx.y * 256 + threadIdx.x;  // 0..2303
    if (m >= MPAD) return;
    const bool valid = (m < M_OUT);
    f16x8 chv, clv, shv, slv;
    for (int j = 0; j < 8; ++j) {
        float cc = 0.f, ss = 0.f;
        if (valid) {
            int kk = c * 8 + j;
            float ang = CW * (float)(m * kk);      // m*kk < 2^24 -> exact
            sincosf(ang, &ss, &cc);
        }
        f16 h, l;
        split_f16(cc, h, l); chv[j] = h; clv[j] = l;
        split_f16(ss, h, l); shv[j] = h; slv[j] = l;
    }
    size_t idx = ((size_t)c * MPAD + m) * 8;
    *(f16x8*)(tbl + idx)                 = chv;
    *(f16x8*)(tbl + A_ELEMS + idx)       = clv;
    *(f16x8*)(tbl + 2 * A_ELEMS + idx)   = shv;
    *(f16x8*)(tbl + 3 * A_ELEMS + idx)   = slv;
}

__global__ void fill_X_cm(const float* __restrict__ x, const float* __restrict__ meanv,
                          f16* __restrict__ xtbl) {
    const int c = blockIdx.x;                      // k-chunk 0..511
    const int n = blockIdx.y * 256 + threadIdx.x;  // 0..4095
    f16x8 hv, lv;
    for (int j = 0; j < 8; ++j) {
        int k = c * 8 + j;
        float v = x[(size_t)k * NDIM + n] - meanv[k];
        f16 h, l;
        split_f16(v, h, l);
        hv[j] = h; lv[j] = l;
    }
    size_t idx = ((size_t)c * NDIM + n) * 8;
    *(f16x8*)(xtbl + idx)           = hv;
    *(f16x8*)(xtbl + X_ELEMS + idx) = lv;
}

// Fused split-f16 DFT GEMM + argmax.
// A fragments: direct global->VGPR, pipelined one segment ahead.
// X: register-mediated staging into double-buffered LDS:
//   segment i: ds_write(xr_i) [waits xr loads from seg i-1] -> barrier ->
//              issue global loads xr_{i+1} + A_{i+1} -> 48 MFMA from sX[buf]
// so the vmcnt wait lands AFTER compute (steady-state vmcnt never drains to 0
// before MFMA). One barrier per segment; ping-pong buffers make write/read
// of different segments race-free.
// Tile: BM=64 x BN=128 x BK=32/segment. 256 threads = 4 waves (2x2 of 32x64).
__global__ __launch_bounds__(256, 2) void dft_gemm_rs(
    const f16* __restrict__ atbl, const f16* __restrict__ xtbl,
    u64* __restrict__ cells)
{
    __shared__ alignas(16) f16 sX0[2][4][128][8];   // [tbl][chunk][n][8] = 16 KB
    __shared__ alignas(16) f16 sX1[2][4][128][8];   // 16 KB

    const int t = threadIdx.x;
    const int n0      = blockIdx.x * 128;
    const int rowBase = blockIdx.y * 64;

    const int lane = t & 63;
    const int w  = t >> 6;
    const int wm = w >> 1, wn = w & 1;
    const int q  = lane >> 4, ln = lane & 15;

    f32x4 aC0[2][4], aC1[2][4], aS0[2][4], aS1[2][4];
#pragma unroll
    for (int i = 0; i < 2; ++i)
#pragma unroll
        for (int j = 0; j < 4; ++j) {
            aC0[i][j] = (f32x4){0.f, 0.f, 0.f, 0.f};
            aC1[i][j] = (f32x4){0.f, 0.f, 0.f, 0.f};
            aS0[i][j] = (f32x4){0.f, 0.f, 0.f, 0.f};
            aS1[i][j] = (f32x4){0.f, 0.f, 0.f, 0.f};
        }

    // ---- X staging map: 4 ops x 256 threads x 16B = one 16 KB K32 tile ----
    // e = o*256 + t  ->  tb = e>>9, ch = (e>>7)&3, col = e&127
    int xtb[4], xch[4], xcol[4];
#pragma unroll
    for (int o = 0; o < 4; ++o) {
        int e = o * 256 + t;
        xtb[o] = e >> 9; xch[o] = (e >> 7) & 3; xcol[o] = e & 127;
    }

    auto loadX = [&](f16x8 (&xr)[4], int kc) {
#pragma unroll
        for (int o = 0; o < 4; ++o)
            xr[o] = *(const f16x8*)(xtbl + (size_t)xtb[o] * X_ELEMS
                     + (((size_t)(kc + xch[o]) * NDIM) + n0 + xcol[o]) * 8);
    };
    auto writeX = [&](f16x8 (&xr)[4], f16 (&dst)[2][4][128][8]) {
#pragma unroll
        for (int o = 0; o < 4; ++o)
            *(f16x8*)&dst[xtb[o]][xch[o]][xcol[o]][0] = xr[o];
    };

    // ---- A pipeline: lane fragment = contiguous 16B, chunk = kc + q ----
    const f16* aBase = atbl + ((size_t)q * MPAD + (rowBase + wm * 32 + ln)) * 8;
    auto loadA = [&](f16x8 (&dst)[2][4], int kc) {
#pragma unroll
        for (int tm = 0; tm < 2; ++tm)
#pragma unroll
            for (int tb = 0; tb < 4; ++tb)
                dst[tm][tb] = *(const f16x8*)(aBase + (size_t)tb * A_ELEMS
                              + ((size_t)kc * MPAD + tm * 16) * 8);
    };

    auto compute = [&](f16x8 (&A)[2][4], const f16 (&buf)[2][4][128][8]) {
        f16x8 bh[4], bl[4];
#pragma unroll
        for (int tn = 0; tn < 4; ++tn) {
            int nl = wn * 64 + tn * 16 + ln;
            bh[tn] = *(const f16x8*)&buf[0][q][nl][0];
            bl[tn] = *(const f16x8*)&buf[1][q][nl][0];
        }
#pragma unroll
        for (int tm = 0; tm < 2; ++tm)
#pragma unroll
            for (int tn = 0; tn < 4; ++tn) {
                aC0[tm][tn] = __builtin_amdgcn_mfma_f32_16x16x32_f16(A[tm][0], bh[tn], aC0[tm][tn], 0, 0, 0);
                aC1[tm][tn] = __builtin_amdgcn_mfma_f32_16x16x32_f16(A[tm][0], bl[tn], aC1[tm][tn], 0, 0, 0);
                aC1[tm][tn] = __builtin_amdgcn_mfma_f32_16x16x32_f16(A[tm][1], bh[tn], aC1[tm][tn], 0, 0, 0);
                aS0[tm][tn] = __builtin_amdgcn_mfma_f32_16x16x32_f16(A[tm][2], bh[tn], aS0[tm][tn], 0, 0, 0);
                aS1[tm][tn] = __builtin_amdgcn_mfma_f32_16x16x32_f16(A[tm][2], bl[tn], aS1[tm][tn], 0, 0, 0);
                aS1[tm][tn] = __builtin_amdgcn_mfma_f32_16x16x32_f16(A[tm][3], bh[tn], aS1[tm][tn], 0, 0, 0);
            }
    };

    f16x8 xr[4];
    f16x8 Aa[2][4], Ab[2][4];
    loadX(xr, 0);
    loadA(Aa, 0);
    for (int kc = 0; kc < 512; kc += 8) {
        // ---- segment A: tile kc via sX0 ----
        writeX(xr, sX0);                 // waits on xr loads (issued last segment)
        __syncthreads();
        loadX(xr, (kc + 4) & 511);       // in flight during compute
        loadA(Ab, (kc + 4) & 511);
        compute(Aa, sX0);
        // ---- segment B: tile kc+4 via sX1 ----
        writeX(xr, sX1);
        __syncthreads();
        loadX(xr, (kc + 8) & 511);
        loadA(Aa, (kc + 8) & 511);
        compute(Ab, sX1);
    }

    // ---- epilogue: amp^2, per-row argmax, atomicMax into cells ----
    const float inv64 = 0.015625f;
#pragma unroll
    for (int tm = 0; tm < 2; ++tm) {
#pragma unroll
        for (int r = 0; r < 4; ++r) {
            u64 best = 0ull;
#pragma unroll
            for (int tn = 0; tn < 4; ++tn) {
                float C = aC0[tm][tn][r] + aC1[tm][tn][r] * inv64;
                float S = aS0[tm][tn][r] + aS1[tm][tn][r] * inv64;
                float a2 = C * C + S * S;
                int col = n0 + wn * 64 + tn * 16 + ln;
                u64 key = ((u64)__float_as_uint(a2) << 32) | (unsigned)(~col);
                if (key > best) best = key;
            }
            for (int off = 1; off < 16; off <<= 1) {
                unsigned hi = (unsigned)(best >> 32), lo = (unsigned)best;
                unsigned ho = __shfl_xor(hi, off);
                unsigned lo2 = __shfl_xor(lo, off);
                u64 o = ((u64)ho << 32) | lo2;
                if (o > best) best = o;
            }
            if (ln == 0) {
                int grow = rowBase + wm * 32 + tm * 16 + q * 4 + r;
                if (grow < M_OUT) atomicMax(cells + grow, best);
            }
        }
    }
}

// ================= MID/LOW fallback path =================
__global__ void fill_tables_rm(f16* __restrict__ tbl) {
    long long g = (long long)blockIdx.x * 256 + threadIdx.x;
    if (g >= (long long)(MPAD * 512)) return;
    int m  = (int)(g >> 9);
    int kq = ((int)g & 511) * 8;
    bool valid = (m < M_OUT);
    f16x8 chv, clv, shv, slv;
    for (int j = 0; j < 8; ++j) {
        float c = 0.f, s = 0.f;
        if (valid) {
            int kk = kq + j;
            float ang = CW * (float)(m * kk);
            sincosf(ang, &s, &c);
        }
        f16 h, l;
        split_f16(c, h, l); chv[j] = h; clv[j] = l;
        split_f16(s, h, l); shv[j] = h; slv[j] = l;
    }
    size_t idx = (size_t)m * NDIM + kq;
    *(f16x8*)(tbl + idx)               = chv;
    *(f16x8*)(tbl + A_ELEMS + idx)     = clv;
    *(f16x8*)(tbl + 2 * A_ELEMS + idx) = shv;
    *(f16x8*)(tbl + 3 * A_ELEMS + idx) = slv;
}

#define PK 40   // padded k-stride: all 8 bank groups covered -> 2-way (free)
__global__ __launch_bounds__(256, 2) void dft_gemm_fb(
    const float* __restrict__ x, const float* __restrict__ meanv,
    const f16* __restrict__ tbl, int useTbl,
    u64* __restrict__ cells)
{
    __shared__ alignas(16) f16 Ach[64][PK];
    __shared__ alignas(16) f16 Acl[64][PK];
    __shared__ alignas(16) f16 Ash[64][PK];
    __shared__ alignas(16) f16 Asl[64][PK];
    __shared__ alignas(16) f16 Xh[128][PK];
    __shared__ alignas(16) f16 Xl[128][PK];

    const int t = threadIdx.x;
    const int n0      = blockIdx.x * 128;
    const int rowBase = blockIdx.y * 64;

    const int am  = t >> 2;
    const int akq = (t & 3) * 8;
    const int xn  = t & 127;
    const int xkh = (t >> 7) * 16;

    const int lane = t & 63;
    const int w  = t >> 6;
    const int wm = w >> 1, wn = w & 1;
    const int q  = lane >> 4, ln = lane & 15;

    f32x4 aC0[2][4], aC1[2][4], aS0[2][4], aS1[2][4];
    for (int i = 0; i < 2; ++i)
        for (int j = 0; j < 4; ++j) {
            aC0[i][j] = (f32x4){0.f, 0.f, 0.f, 0.f};
            aC1[i][j] = (f32x4){0.f, 0.f, 0.f, 0.f};
            aS0[i][j] = (f32x4){0.f, 0.f, 0.f, 0.f};
            aS1[i][j] = (f32x4){0.f, 0.f, 0.f, 0.f};
        }

    const int arow = rowBase + am;
    const bool avalid = (arow < M_OUT);

    for (int k0 = 0; k0 < NDIM; k0 += 32) {
        __syncthreads();
        if (useTbl) {
            size_t idx = (size_t)arow * NDIM + k0 + akq;
            *(f16x8*)&Ach[am][akq] = *(const f16x8*)(tbl + idx);
            *(f16x8*)&Acl[am][akq] = *(const f16x8*)(tbl + A_ELEMS + idx);
            *(f16x8*)&Ash[am][akq] = *(const f16x8*)(tbl + 2 * A_ELEMS + idx);
            *(f16x8*)&Asl[am][akq] = *(const f16x8*)(tbl + 3 * A_ELEMS + idx);
        } else {
            f16x8 chv, clv, shv, slv;
            for (int j = 0; j < 8; ++j) {
                float c = 0.f, s = 0.f;
                if (avalid) {
                    int kk = k0 + akq + j;
                    float ang = CW * (float)(arow * kk);
                    sincosf(ang, &s, &c);
                }
                f16 h, l;
                split_f16(c, h, l); chv[j] = h; clv[j] = l;
                split_f16(s, h, l); shv[j] = h; slv[j] = l;
            }
            *(f16x8*)&Ach[am][akq] = chv;
            *(f16x8*)&Acl[am][akq] = clv;
            *(f16x8*)&Ash[am][akq] = shv;
            *(f16x8*)&Asl[am][akq] = slv;
        }
        {
            const float* xp = x + (size_t)(k0 + xkh) * NDIM + n0 + xn;
            f16x8 h0, h1, l0, l1;
            for (int r = 0; r < 16; ++r) {
                float v = xp[(size_t)r * NDIM] - meanv[k0 + xkh + r];
                f16 hi, lo;
                split_f16(v, hi, lo);
                if (r < 8) { h0[r] = hi; l0[r] = lo; }
                else       { h1[r - 8] = hi; l1[r - 8] = lo; }
            }
            *(f16x8*)&Xh[xn][xkh]     = h0;
            *(f16x8*)&Xh[xn][xkh + 8] = h1;
            *(f16x8*)&Xl[xn][xkh]     = l0;
            *(f16x8*)&Xl[xn][xkh + 8] = l1;
        }
        __syncthreads();
        f16x8 fch[2], fcl[2], fsh[2], fsl[2], bh[4], bl[4];
        for (int tm = 0; tm < 2; ++tm) {
            int ml = wm * 32 + tm * 16 + ln;
            fch[tm] = *(const f16x8*)&Ach[ml][q * 8];
            fcl[tm] = *(const f16x8*)&Acl[ml][q * 8];
            fsh[tm] = *(const f16x8*)&Ash[ml][q * 8];
            fsl[tm] = *(const f16x8*)&Asl[ml][q * 8];
        }
        for (int tn = 0; tn < 4; ++tn) {
            int nl = wn * 64 + tn * 16 + ln;
            bh[tn] = *(const f16x8*)&Xh[nl][q * 8];
            bl[tn] = *(const f16x8*)&Xl[nl][q * 8];
        }
        for (int tm = 0; tm < 2; ++tm)
            for (int tn = 0; tn < 4; ++tn) {
                aC0[tm][tn] = __builtin_amdgcn_mfma_f32_16x16x32_f16(fch[tm], bh[tn], aC0[tm][tn], 0, 0, 0);
                aC1[tm][tn] = __builtin_amdgcn_mfma_f32_16x16x32_f16(fch[tm], bl[tn], aC1[tm][tn], 0, 0, 0);
                aC1[tm][tn] = __builtin_amdgcn_mfma_f32_16x16x32_f16(fcl[tm], bh[tn], aC1[tm][tn], 0, 0, 0);
                aS0[tm][tn] = __builtin_amdgcn_mfma_f32_16x16x32_f16(fsh[tm], bh[tn], aS0[tm][tn], 0, 0, 0);
                aS1[tm][tn] = __builtin_amdgcn_mfma_f32_16x16x32_f16(fsh[tm], bl[tn], aS1[tm][tn], 0, 0, 0);
                aS1[tm][tn] = __builtin_amdgcn_mfma_f32_16x16x32_f16(fsl[tm], bh[tn], aS1[tm][tn], 0, 0, 0);
            }
    }

    const float inv64 = 0.015625f;
    for (int tm = 0; tm < 2; ++tm) {
        for (int r = 0; r < 4; ++r) {
            u64 best = 0ull;
            for (int tn = 0; tn < 4; ++tn) {
                float C = aC0[tm][tn][r] + aC1[tm][tn][r] * inv64;
                float S = aS0[tm][tn][r] + aS1[tm][tn][r] * inv64;
                float a2 = C * C + S * S;
                int col = n0 + wn * 64 + tn * 16 + ln;
                u64 key = ((u64)__float_as_uint(a2) << 32) | (unsigned)(~col);
                if (key > best) best = key;
            }
            for (int off = 1; off < 16; off <<= 1) {
                unsigned hi = (unsigned)(best >> 32), lo = (unsigned)best;
                unsigned ho = __shfl_xor(hi, off);
                unsigned lo2 = __shfl_xor(lo, off);
                u64 o = ((u64)ho << 32) | lo2;
                if (o > best) best = o;
            }
            if (ln == 0) {
                int grow = rowBase + wm * 32 + tm * 16 + q * 4 + r;
                if (grow < M_OUT) atomicMax(cells + grow, best);
            }
        }
    }
}

// ---------------- cells -> output ----------------
__global__ void out_kernel(const u64* __restrict__ cells, float* __restrict__ out) {
    int i = blockIdx.x * 256 + threadIdx.x;
    if (i < M_OUT) {
        unsigned col = ~(unsigned)(cells[i] & 0xFFFFFFFFull);
        float freq = (float)col / (4096.0f / 30.0f);
        out[i] = freq * 60.0f;
    }
}

extern "C" void kernel_launch(void* const* d_in, const int* in_sizes, int n_in,
                              void* d_out, int out_size, void* d_ws, size_t ws_size,
                              hipStream_t stream) {
    const float* x = (const float*)d_in[0];
    char* ws = (char*)d_ws;
    float* meanv = (float*)(ws + WS_MEAN);
    u64*   cells = (u64*)(ws + WS_CELLS);
    f16*   atbl  = (f16*)(ws + WS_TBL);
    f16*   xtbl  = (f16*)(ws + WS_XTBL);
    float* out   = (float*)d_out;

    hipLaunchKernelGGL(init_cells, dim3((M_OUT + 255) / 256), dim3(256), 0, stream, cells);
    hipLaunchKernelGGL(mean_kernel, dim3(NDIM), dim3(256), 0, stream, x, meanv);

    if (ws_size >= WS_FULL_END) {
        hipLaunchKernelGGL(fill_A_cm, dim3(512, 9), dim3(256), 0, stream, atbl);
        hipLaunchKernelGGL(fill_X_cm, dim3(512, 16), dim3(256), 0, stream, x, meanv, xtbl);
        hipLaunchKernelGGL(dft_gemm_rs, dim3(32, 33), dim3(256), 0, stream, atbl, xtbl, cells);
    } else if (ws_size >= WS_MID_END) {
        hipLaunchKernelGGL(fill_tables_rm, dim3(4224), dim3(256), 0, stream, atbl);
        hipLaunchKernelGGL(dft_gemm_fb, dim3(32, 33), dim3(256), 0, stream,
                           x, meanv, atbl, 1, cells);
    } else {
        hipLaunchKernelGGL(dft_gemm_fb, dim3(32, 33), dim3(256), 0, stream,
                           x, meanv, atbl, 0, cells);
    }
    hipLaunchKernelGGL(out_kernel, dim3((M_OUT + 255) / 256), dim3(256), 0, stream, cells, out);
}